// Round 2
// baseline (191.488 us; speedup 1.0000x reference)
//
#include <hip/hip_runtime.h>

typedef unsigned short u16;
typedef unsigned int u32;
typedef __attribute__((ext_vector_type(8))) short short8;
typedef __attribute__((ext_vector_type(4))) float floatx4;

#define NUMS 2048
#define DIM 128
#define ROWS_TOT 16384
#define HALF_ROWS 8192
#define KTOP 129
#define MTILE 16
#define SCALE 0.08838834764831845f

__device__ __forceinline__ u16 f2bf(float f) {
  u32 u = __builtin_bit_cast(u32, f);
  u += 0x7FFFu + ((u >> 16) & 1u);
  return (u16)(u >> 16);
}
__device__ __forceinline__ float bf2f(u16 b) {
  return __builtin_bit_cast(float, (u32)b << 16);
}

// data fp32 [16384][128] -> db bf16 (same layout)
__global__ void cvt_data_k(const float* __restrict__ d, u16* __restrict__ db) {
  const int i = (blockIdx.x * 256 + threadIdx.x) * 8;
  const float4 a = *(const float4*)(d + i);
  const float4 b = *(const float4*)(d + i + 4);
  short8 v;
  v[0] = (short)f2bf(a.x); v[1] = (short)f2bf(a.y);
  v[2] = (short)f2bf(a.z); v[3] = (short)f2bf(a.w);
  v[4] = (short)f2bf(b.x); v[5] = (short)f2bf(b.y);
  v[6] = (short)f2bf(b.z); v[7] = (short)f2bf(b.w);
  *(short8*)(db + i) = v;
}

// weight fp32 [2048][128] -> wb bf16 [2048][128] + wt bf16 [128][2048]
__global__ void cvt_w_k(const float* __restrict__ w, u16* __restrict__ wb,
                        u16* __restrict__ wt) {
  __shared__ u16 tile[32][33];
  const int tx = threadIdx.x, ty = threadIdx.y;
  const int x = blockIdx.x * 32 + tx;  // col in W (0..127)
  const int y0 = blockIdx.y * 32;      // row block in W
#pragma unroll
  for (int j = 0; j < 32; j += 8) {
    const u16 v = f2bf(w[(size_t)(y0 + ty + j) * DIM + x]);
    wb[(size_t)(y0 + ty + j) * DIM + x] = v;
    tile[ty + j][tx] = v;
  }
  __syncthreads();
  const int x2 = y0 + tx;               // col in Wt (= row in W)
  const int y2 = blockIdx.x * 32 + ty;  // row in Wt (= col in W)
#pragma unroll
  for (int j = 0; j < 32; j += 8)
    wt[(size_t)(y2 + j) * NUMS + x2] = tile[tx][ty + j];
}

// swizzled LDS index for S[row][col]: XOR 8-elem chunk with row
__device__ __forceinline__ int s_idx(int r, int c) {
  return r * NUMS + ((((c >> 3) ^ r) << 3) | (c & 7));
}

__global__ __launch_bounds__(256, 2)
void fused_k(const u16* __restrict__ db, const u16* __restrict__ wb,
             const u16* __restrict__ wt, const float* __restrict__ dataF,
             float* __restrict__ out) {
  __shared__ u16 S[MTILE * NUMS];  // 64 KiB bf16 attention tile, 16 x 2048
  const int r0 = blockIdx.x * MTILE;
  const int lane = threadIdx.x & 63;
  const int wave = threadIdx.x >> 6;
  const int m = lane & 15;
  const int quad = lane >> 4;

  // ---------- GEMM1: attention = sigmoid((data @ W^T)/sqrt(D)) -> LDS bf16 ----
  short8 afrag[4];
  {
    const u16* ap = db + (size_t)(r0 + m) * DIM + quad * 8;
#pragma unroll
    for (int ks = 0; ks < 4; ks++)
      afrag[ks] = *(const short8*)(ap + ks * 32);
  }
#pragma unroll 4
  for (int nt = 0; nt < 32; nt++) {
    const int n0 = wave * 512 + nt * 16;
    const u16* bp = wb + (size_t)(n0 + m) * DIM + quad * 8;
    floatx4 acc = {0.f, 0.f, 0.f, 0.f};
#pragma unroll
    for (int ks = 0; ks < 4; ks++) {
      short8 bfrag = *(const short8*)(bp + ks * 32);
      acc = __builtin_amdgcn_mfma_f32_16x16x32_bf16(afrag[ks], bfrag, acc, 0, 0, 0);
    }
    // C/D layout: col = n0 + (lane&15), row = quad*4 + reg
    const int c = n0 + m;
#pragma unroll
    for (int reg = 0; reg < 4; reg++) {
      const int rr = quad * 4 + reg;
      float att = 1.f / (1.f + __expf(-acc[reg] * SCALE));
      att = fminf(fmaxf(att, 0.f), 1.f);  // IEEE fmax scrubs NaN -> 0
      S[s_idx(rr, c)] = f2bf(att);
    }
  }
  __syncthreads();

  // ---------- first half: read_query = [data_fp32 | attention @ W] ----------
  if (r0 < HALF_ROWS) {
    {  // copy fp32 data -> read_query[:, :128], 32 B per thread
      const int row = threadIdx.x >> 4;
      const int c8 = (threadIdx.x & 15) << 3;
      const float4* src = (const float4*)(dataF + (size_t)(r0 + row) * DIM + c8);
      float4* dst = (float4*)(out + 16384 + (size_t)(r0 + row) * 256 + c8);
      dst[0] = src[0];
      dst[1] = src[1];
    }
    // GEMM2: augment[16][128] = S[16][2048] @ W[2048][128]; B-frags = Wt rows
    const int n0 = wave * 32;
    floatx4 acc0 = {0.f, 0.f, 0.f, 0.f}, acc1 = {0.f, 0.f, 0.f, 0.f};
    const u16* w0 = wt + (size_t)(n0 + m) * NUMS + quad * 8;
    const u16* w1 = w0 + (size_t)16 * NUMS;
#pragma unroll 8
    for (int ks = 0; ks < 64; ks++) {
      const int chunk = ks * 4 + quad;  // A-frag: row m, k = ks*32 + quad*8
      short8 af = *(const short8*)(S + m * NUMS + ((chunk ^ m) << 3));
      short8 b0 = *(const short8*)(w0 + ks * 32);
      short8 b1 = *(const short8*)(w1 + ks * 32);
      acc0 = __builtin_amdgcn_mfma_f32_16x16x32_bf16(af, b0, acc0, 0, 0, 0);
      acc1 = __builtin_amdgcn_mfma_f32_16x16x32_bf16(af, b1, acc1, 0, 0, 0);
    }
#pragma unroll
    for (int reg = 0; reg < 4; reg++) {
      const int row = quad * 4 + reg;
      float* o = out + 16384 + (size_t)(r0 + row) * 256 + 128;
      o[n0 + m] = acc0[reg];
      o[n0 + 16 + m] = acc1[reg];
    }
  }

  // ---------- top-129 mean per row -> mem_score = 1 - mean (fp32) ----------
  for (int rr = wave * 4; rr < wave * 4 + 4; rr++) {
    float vals[32];
#pragma unroll
    for (int i = 0; i < 32; i++)
      vals[i] = bf2f(S[s_idx(rr, i * 64 + lane)]);

    auto count_ge = [&](float thr) {
      int cnt = 0;
#pragma unroll
      for (int i = 0; i < 32; i++) cnt += (vals[i] >= thr) ? 1 : 0;
#pragma unroll
      for (int off = 1; off < 64; off <<= 1) cnt += __shfl_xor(cnt, off);
      return cnt;
    };

    // binary search on bf16 bit patterns (non-negative -> monotone in bits)
    u32 lo = 0u, hi = 0x3F80u;  // [0.0, 1.0]
    if (count_ge(0.25f) >= KTOP) lo = 0x3E80u; else hi = 0x3E80u;
    while (hi - lo > 1u) {
      const u32 mid = (lo + hi) >> 1;
      if (count_ge(bf2f((u16)mid)) >= KTOP) lo = mid; else hi = mid;
    }
    const float vstar = bf2f((u16)lo);

    float s = 0.f;
    int cgt = 0;
#pragma unroll
    for (int i = 0; i < 32; i++) {
      if (vals[i] > vstar) { s += vals[i]; cgt++; }
    }
#pragma unroll
    for (int off = 1; off < 64; off <<= 1) {
      s += __shfl_xor(s, off);
      cgt += __shfl_xor(cgt, off);
    }
    if (lane == 0) {
      const float mean = (s + (float)(KTOP - cgt) * vstar) * (1.f / (float)KTOP);
      out[r0 + rr] = 1.f - mean;
    }
  }
}

extern "C" void kernel_launch(void* const* d_in, const int* in_sizes, int n_in,
                              void* d_out, int out_size, void* d_ws, size_t ws_size,
                              hipStream_t stream) {
  const float* data = (const float*)d_in[0];    // [32,512,128] fp32
  const float* weight = (const float*)d_in[1];  // [2048,128] fp32
  float* out = (float*)d_out;  // 16384 mem_score + 16*512*256 read_query (fp32)

  u16* wt = (u16*)d_ws;          // [128][2048] bf16, 512 KiB
  u16* wb = wt + NUMS * DIM;     // [2048][128] bf16, 512 KiB
  u16* db = wb + NUMS * DIM;     // [16384][128] bf16, 4 MiB

  cvt_w_k<<<dim3(DIM / 32, NUMS / 32), dim3(32, 8), 0, stream>>>(weight, wb, wt);
  cvt_data_k<<<dim3(ROWS_TOT * DIM / (256 * 8)), dim3(256), 0, stream>>>(data, db);
  fused_k<<<dim3(ROWS_TOT / MTILE), dim3(256), 0, stream>>>(db, wb, wt, data, out);
}

// Round 3
// 167.810 us; speedup vs baseline: 1.1411x; 1.1411x over previous
//
#include <hip/hip_runtime.h>

typedef unsigned short u16;
typedef unsigned int u32;
typedef unsigned long long u64;
typedef __attribute__((ext_vector_type(8))) short short8;
typedef __attribute__((ext_vector_type(4))) float floatx4;

#define NUMS 2048
#define DIM 128
#define ROWS_TOT 16384
#define HALF_ROWS 8192
#define KTOP 129
#define MTILE 16
#define SCALE 0.08838834764831845f

__device__ __forceinline__ u16 f2bf(float f) {
  u32 u = __builtin_bit_cast(u32, f);
  u += 0x7FFFu + ((u >> 16) & 1u);
  return (u16)(u >> 16);
}
__device__ __forceinline__ float bf2f(u32 b) {
  return __builtin_bit_cast(float, b << 16);
}

__device__ __forceinline__ short8 pack_bf8(float4 a, float4 b) {
  short8 v;
  v[0] = (short)f2bf(a.x); v[1] = (short)f2bf(a.y);
  v[2] = (short)f2bf(a.z); v[3] = (short)f2bf(a.w);
  v[4] = (short)f2bf(b.x); v[5] = (short)f2bf(b.y);
  v[6] = (short)f2bf(b.z); v[7] = (short)f2bf(b.w);
  return v;
}

// weight fp32 [2048][128] -> wb bf16 [2048][128] + wt bf16 [128][2048]
__global__ void cvt_w_k(const float* __restrict__ w, u16* __restrict__ wb,
                        u16* __restrict__ wt) {
  __shared__ u16 tile[32][33];
  const int tx = threadIdx.x, ty = threadIdx.y;
  const int x = blockIdx.x * 32 + tx;  // col in W (0..127)
  const int y0 = blockIdx.y * 32;      // row block in W
#pragma unroll
  for (int j = 0; j < 32; j += 8) {
    const u16 v = f2bf(w[(size_t)(y0 + ty + j) * DIM + x]);
    wb[(size_t)(y0 + ty + j) * DIM + x] = v;
    tile[ty + j][tx] = v;
  }
  __syncthreads();
  const int x2 = y0 + tx;               // col in Wt (= row in W)
  const int y2 = blockIdx.x * 32 + ty;  // row in Wt (= col in W)
#pragma unroll
  for (int j = 0; j < 32; j += 8)
    wt[(size_t)(y2 + j) * NUMS + x2] = tile[tx][ty + j];
}

// swizzled LDS index for S[row][col]: XOR 8-elem chunk id with row
__device__ __forceinline__ int s_idx(int r, int c) {
  return r * NUMS + ((((c >> 3) ^ r) << 3) | (c & 7));
}

__global__ __launch_bounds__(512, 4)
void fused_k(const float* __restrict__ dataF, const u16* __restrict__ wb,
             const u16* __restrict__ wt, float* __restrict__ out) {
  __shared__ u16 S[MTILE * NUMS];  // 64 KiB bf16 attention tile, 16 x 2048
  const int tid = threadIdx.x;
  const int r0 = blockIdx.x * MTILE;
  const int lane = tid & 63;
  const int wave = tid >> 6;   // 0..7
  const int m = lane & 15;
  const int quad = lane >> 4;

  // ---------- GEMM1: attention = sigmoid((data @ W^T)/sqrt(D)) -> LDS bf16 ----
  short8 afrag[4];
  {
    const float* ap = dataF + (size_t)(r0 + m) * DIM + quad * 8;
#pragma unroll
    for (int ks = 0; ks < 4; ks++) {
      const float4 x = *(const float4*)(ap + ks * 32);
      const float4 y = *(const float4*)(ap + ks * 32 + 4);
      afrag[ks] = pack_bf8(x, y);
    }
  }
#pragma unroll 4
  for (int nt = 0; nt < 16; nt++) {
    const int n0 = wave * 256 + nt * 16;
    const u16* bp = wb + (size_t)(n0 + m) * DIM + quad * 8;
    floatx4 acc = {0.f, 0.f, 0.f, 0.f};
#pragma unroll
    for (int ks = 0; ks < 4; ks++) {
      short8 bfrag = *(const short8*)(bp + ks * 32);
      acc = __builtin_amdgcn_mfma_f32_16x16x32_bf16(afrag[ks], bfrag, acc, 0, 0, 0);
    }
    // C/D layout: col = n0 + (lane&15), row = quad*4 + reg
    const int c = n0 + m;
#pragma unroll
    for (int reg = 0; reg < 4; reg++) {
      const int rr = quad * 4 + reg;
      float att = 1.f / (1.f + __expf(-acc[reg] * SCALE));
      att = fminf(fmaxf(att, 0.f), 1.f);  // IEEE fmax scrubs NaN -> 0
      S[s_idx(rr, c)] = f2bf(att);
    }
  }
  __syncthreads();

  // ---------- first half: read_query = [data_fp32 | attention @ W] ----------
  if (r0 < HALF_ROWS) {
    {  // copy fp32 data -> read_query[:, :128]; 512 thr x 16B = 16 rows x 512B
      const int row = tid >> 5;
      const int c4 = (tid & 31) << 2;
      *(float4*)(out + 16384 + (size_t)(r0 + row) * 256 + c4) =
          *(const float4*)(dataF + (size_t)(r0 + row) * DIM + c4);
    }
    // GEMM2: augment[16][128] = S @ W; each wave owns 16 cols (n0 = wave*16)
    const int n0 = wave * 16;
    floatx4 acc = {0.f, 0.f, 0.f, 0.f};
    const u16* w0 = wt + (size_t)(n0 + m) * NUMS + quad * 8;
#pragma unroll 8
    for (int ks = 0; ks < 64; ks++) {
      const int chunk = ks * 4 + quad;  // A-frag: row m, k = ks*32 + quad*8
      short8 af = *(const short8*)(S + m * NUMS + ((chunk ^ m) << 3));
      short8 b0 = *(const short8*)(w0 + ks * 32);
      acc = __builtin_amdgcn_mfma_f32_16x16x32_bf16(af, b0, acc, 0, 0, 0);
    }
#pragma unroll
    for (int reg = 0; reg < 4; reg++) {
      const int row = quad * 4 + reg;
      out[16384 + (size_t)(r0 + row) * 256 + 128 + n0 + m] = acc[reg];
    }
  }

  // ---------- top-129 mean per row -> mem_score = 1 - mean (fp32) ----------
#pragma unroll
  for (int rv = 0; rv < 2; rv++) {
    const int rr = wave * 2 + rv;
    // load the row's 2048 bf16 bits; physical-chunk order (partition-agnostic)
    u32 bits[32];
#pragma unroll
    for (int j = 0; j < 4; j++) {
      const short8 v = *(const short8*)(S + rr * NUMS + (j * 64 + lane) * 8);
#pragma unroll
      for (int t = 0; t < 8; t++) bits[j * 8 + t] = (u32)(u16)v[t];
    }

    // wave-uniform count of (bits >= t) via ballot + popcount (SALU reduce)
    auto count_ge = [&](u32 t) -> int {
      int c = 0;
#pragma unroll
      for (int i = 0; i < 32; i++)
        c += __popcll(__ballot(bits[i] >= t));
      return c;
    };

    // phase 0: 8 independent coarse thresholds 0x3EE0..0x3F50 (0.4375..0.8125)
    int cnt[8];
#pragma unroll
    for (int j = 0; j < 8; j++) cnt[j] = count_ge(0x3EE0u + ((u32)j << 4));
    u32 lo = 0u, hi = 0x3F81u;  // cnt(0)=2048>=K; all vals <= 1.0 < 0x3F81
#pragma unroll
    for (int j = 0; j < 8; j++)
      if (cnt[j] >= KTOP) lo = 0x3EE0u + ((u32)j << 4);
#pragma unroll
    for (int j = 7; j >= 0; j--)
      if (cnt[j] < KTOP) hi = 0x3EE0u + ((u32)j << 4);

    // phase 1: binary search (typically 4 iters; bits are monotone, vals >= 0)
    while (hi - lo > 1u) {
      const u32 mid = (lo + hi) >> 1;
      if (count_ge(mid) >= KTOP) lo = mid; else hi = mid;
    }
    const float vstar = bf2f(lo);

    // exact top-K sum: sum(> v*) + (K - cnt(> v*)) * v*
    float s = 0.f;
    int cgt = 0;
#pragma unroll
    for (int i = 0; i < 32; i++) {
      if (bits[i] > lo) s += bf2f(bits[i]);
      cgt += __popcll(__ballot(bits[i] > lo));
    }
#pragma unroll
    for (int off = 1; off < 64; off <<= 1) s += __shfl_xor(s, off);
    if (lane == 0) {
      const float mean = (s + (float)(KTOP - cgt) * vstar) * (1.f / (float)KTOP);
      out[r0 + rr] = 1.f - mean;
    }
  }
}

extern "C" void kernel_launch(void* const* d_in, const int* in_sizes, int n_in,
                              void* d_out, int out_size, void* d_ws, size_t ws_size,
                              hipStream_t stream) {
  const float* data = (const float*)d_in[0];    // [32,512,128] fp32
  const float* weight = (const float*)d_in[1];  // [2048,128] fp32
  float* out = (float*)d_out;  // 16384 mem_score + 16*512*256 read_query (fp32)

  u16* wt = (u16*)d_ws;       // [128][2048] bf16, 512 KiB
  u16* wb = wt + NUMS * DIM;  // [2048][128] bf16, 512 KiB

  cvt_w_k<<<dim3(DIM / 32, NUMS / 32), dim3(32, 8), 0, stream>>>(weight, wb, wt);
  fused_k<<<dim3(ROWS_TOT / MTILE), dim3(512), 0, stream>>>(data, wb, wt, out);
}

// Round 4
// 162.059 us; speedup vs baseline: 1.1816x; 1.0355x over previous
//
#include <hip/hip_runtime.h>

typedef unsigned short u16;
typedef unsigned int u32;
typedef __attribute__((ext_vector_type(8))) short short8;
typedef __attribute__((ext_vector_type(4))) float floatx4;

#define NUMS 2048
#define DIM 128
#define ROWS_TOT 16384
#define HALF_ROWS 8192
#define KTOP 129
#define MTILE 16
#define SP 2056  // padded S row stride (elems): breaks bank alignment, keeps b64/b128 alignment
#define SCALE 0.08838834764831845f

__device__ __forceinline__ u16 f2bf(float f) {
  u32 u = __builtin_bit_cast(u32, f);
  u += 0x7FFFu + ((u >> 16) & 1u);
  return (u16)(u >> 16);
}
__device__ __forceinline__ float bf2f(u32 b) {
  return __builtin_bit_cast(float, b << 16);
}

// weight fp32 [2048][128] -> wb bf16 [2048][128] + wt bf16 [128][2048]
__global__ void cvt_w_k(const float* __restrict__ w, u16* __restrict__ wb,
                        u16* __restrict__ wt) {
  __shared__ u16 tile[32][33];
  const int tx = threadIdx.x, ty = threadIdx.y;
  const int x = blockIdx.x * 32 + tx;  // col in W (0..127)
  const int y0 = blockIdx.y * 32;      // row block in W
#pragma unroll
  for (int j = 0; j < 32; j += 8) {
    const u16 v = f2bf(w[(size_t)(y0 + ty + j) * DIM + x]);
    wb[(size_t)(y0 + ty + j) * DIM + x] = v;
    tile[ty + j][tx] = v;
  }
  __syncthreads();
  const int x2 = y0 + tx;               // col in Wt (= row in W)
  const int y2 = blockIdx.x * 32 + ty;  // row in Wt (= col in W)
#pragma unroll
  for (int j = 0; j < 32; j += 8)
    wt[(size_t)(y2 + j) * NUMS + x2] = tile[tx][ty + j];
}

__global__ __launch_bounds__(512, 4)
void fused_k(const float* __restrict__ dataF, const u16* __restrict__ wb,
             const u16* __restrict__ wt, float* __restrict__ out) {
  __shared__ u16 S[MTILE * SP];  // 65792 B: att tile, S[data-row][att-col]
  const int tid = threadIdx.x;
  const int r0 = blockIdx.x * MTILE;
  const int lane = tid & 63;
  const int wave = tid >> 6;  // 0..7
  const int m = lane & 15;
  const int quad = lane >> 4;

  // ---- B-operand fragments: data rows, fp32 -> bf16 inline ----
  short8 dfrag[4];
  {
    const float* ap = dataF + (size_t)(r0 + m) * DIM + quad * 8;
#pragma unroll
    for (int ks = 0; ks < 4; ks++) {
      const float4 x = *(const float4*)(ap + ks * 32);
      const float4 y = *(const float4*)(ap + ks * 32 + 4);
      short8 v;
      v[0] = (short)f2bf(x.x); v[1] = (short)f2bf(x.y);
      v[2] = (short)f2bf(x.z); v[3] = (short)f2bf(x.w);
      v[4] = (short)f2bf(y.x); v[5] = (short)f2bf(y.y);
      v[6] = (short)f2bf(y.z); v[7] = (short)f2bf(y.w);
      dfrag[ks] = v;
    }
  }

  // ---- GEMM1 (transposed): D[att-col][data-row] = W * data^T ----
  // C-layout: lane holds data-row = m, att-cols = n0 + quad*4 + {0..3}
  u16* sbase = S + m * SP + wave * 256 + quad * 4;
#pragma unroll 4
  for (int nt = 0; nt < 16; nt++) {
    const int n0 = wave * 256 + nt * 16;
    const u16* wp = wb + (size_t)(n0 + m) * DIM + quad * 8;
    floatx4 acc = {0.f, 0.f, 0.f, 0.f};
#pragma unroll
    for (int ks = 0; ks < 4; ks++) {
      const short8 wfrag = *(const short8*)(wp + ks * 32);
      acc = __builtin_amdgcn_mfma_f32_16x16x32_bf16(wfrag, dfrag[ks], acc, 0, 0, 0);
    }
    float a0 = 1.f / (1.f + __expf(-acc[0] * SCALE));
    float a1 = 1.f / (1.f + __expf(-acc[1] * SCALE));
    float a2 = 1.f / (1.f + __expf(-acc[2] * SCALE));
    float a3 = 1.f / (1.f + __expf(-acc[3] * SCALE));
    uint2 p;
    p.x = (u32)f2bf(a0) | ((u32)f2bf(a1) << 16);
    p.y = (u32)f2bf(a2) | ((u32)f2bf(a3) << 16);
    *(uint2*)(sbase + nt * 16) = p;  // 4 consecutive att-cols, one b64 write
  }
  __syncthreads();

  // ---- first half: read_query = [data_fp32 | attention @ W] ----
  if (r0 < HALF_ROWS) {
    {  // copy fp32 data -> read_query[:, :128]
      const int row = tid >> 5;
      const int c4 = (tid & 31) << 2;
      *(float4*)(out + 16384 + (size_t)(r0 + row) * 256 + c4) =
          *(const float4*)(dataF + (size_t)(r0 + row) * DIM + c4);
    }
    // GEMM2 (transposed): D[out-col][data-row] = W^T * att^T
    // A-frag: wt rows (out-cols), B-frag: S rows (att by data-row)
    const int n0 = wave * 16;
    const u16* wtp = wt + (size_t)(n0 + m) * NUMS + quad * 8;
    const u16* sp2 = S + m * SP + quad * 8;
    floatx4 acc = {0.f, 0.f, 0.f, 0.f};
#pragma unroll 8
    for (int ks = 0; ks < 64; ks++) {
      const short8 a = *(const short8*)(wtp + ks * 32);  // imm offsets ks*64B
      const short8 b = *(const short8*)(sp2 + ks * 32);
      acc = __builtin_amdgcn_mfma_f32_16x16x32_bf16(a, b, acc, 0, 0, 0);
    }
    // lane: data-row m, out-cols n0 + quad*4 + {0..3} -> one dwordx4 store
    float4 st;
    st.x = acc[0]; st.y = acc[1]; st.z = acc[2]; st.w = acc[3];
    *(float4*)(out + 16384 + (size_t)(r0 + m) * 256 + 128 + n0 + quad * 4) = st;
  }

  // ---- top-129 mean per row -> mem_score = 1 - mean ----
#pragma unroll
  for (int rv = 0; rv < 2; rv++) {
    const int rr = wave * 2 + rv;
    const u16* rp = S + rr * SP + lane * 8;  // 16 B per lane per chunk
    u32 x[16], xh[16];
#pragma unroll
    for (int j = 0; j < 4; j++) {
      const short8 v = *(const short8*)(rp + j * 512);
      const u32* pv = (const u32*)&v;
      x[j * 4 + 0] = pv[0]; x[j * 4 + 1] = pv[1];
      x[j * 4 + 2] = pv[2]; x[j * 4 + 3] = pv[3];
    }
#pragma unroll
    for (int i = 0; i < 16; i++) xh[i] = x[i] | 0x80008000u;

    // per-lane count of (bf16 code >= t), two codes per dword (SWAR)
    auto cnt_ge = [&](u32 t) -> int {
      const u32 t2 = t * 0x10001u;
      int c = 0;
#pragma unroll
      for (int i = 0; i < 16; i++)
        c += __popc((xh[i] - t2) & 0x80008000u);
      return c;
    };

    // 8 independent counts at consecutive codes 0x3F00..0x3F07 (atts ~0.5+-0.06)
    int c8[8];
#pragma unroll
    for (int j = 0; j < 8; j++) c8[j] = cnt_ge(0x3F00u + (u32)j);
    u32 pk[4];
#pragma unroll
    for (int j = 0; j < 4; j++) pk[j] = (u32)c8[2 * j] | ((u32)c8[2 * j + 1] << 16);
#pragma unroll
    for (int off = 1; off < 64; off <<= 1) {
#pragma unroll
      for (int j = 0; j < 4; j++) pk[j] += __shfl_xor(pk[j], off);
    }
    int cw[8];
#pragma unroll
    for (int j = 0; j < 4; j++) {
      cw[2 * j] = (int)(pk[j] & 0xFFFFu);
      cw[2 * j + 1] = (int)(pk[j] >> 16);
    }

    u32 lo;
    int cgt;
    if (cw[0] >= KTOP && cw[7] < KTOP) {  // 129th value inside the window
      int idx = 0;
#pragma unroll
      for (int j = 1; j < 8; j++) idx += (cw[j] >= KTOP) ? 1 : 0;  // counts monotone
      lo = 0x3F00u + (u32)idx;
      cgt = cw[idx + 1];  // idx <= 6 guaranteed by window test
    } else {  // fallback: full binary search over bf16 codes (cold, never in practice)
      u32 L = 0u, H = 0x3F81u;
      while (H - L > 1u) {
        const u32 mid = (L + H) >> 1;
        int cc = cnt_ge(mid);
#pragma unroll
        for (int off = 1; off < 64; off <<= 1) cc += __shfl_xor(cc, off);
        if (cc >= KTOP) L = mid; else H = mid;
      }
      lo = L;
      int cg = cnt_ge(lo + 1);
#pragma unroll
      for (int off = 1; off < 64; off <<= 1) cg += __shfl_xor(cg, off);
      cgt = cg;
    }

    // exact top-K sum: sum(vals > v*) + (K - cnt_gt) * v*
    const float vstar = bf2f(lo);
    float s = 0.f;
#pragma unroll
    for (int i = 0; i < 16; i++) {
      const float v0 = bf2f(x[i] & 0xFFFFu);
      const float v1 = __builtin_bit_cast(float, x[i] & 0xFFFF0000u);
      if (v0 > vstar) s += v0;
      if (v1 > vstar) s += v1;
    }
#pragma unroll
    for (int off = 1; off < 64; off <<= 1) s += __shfl_xor(s, off);
    if (lane == 0) {
      const float mean = (s + (float)(KTOP - cgt) * vstar) * (1.f / (float)KTOP);
      out[r0 + rr] = 1.f - mean;
    }
  }
}

extern "C" void kernel_launch(void* const* d_in, const int* in_sizes, int n_in,
                              void* d_out, int out_size, void* d_ws, size_t ws_size,
                              hipStream_t stream) {
  const float* data = (const float*)d_in[0];    // [32,512,128] fp32
  const float* weight = (const float*)d_in[1];  // [2048,128] fp32
  float* out = (float*)d_out;  // 16384 mem_score + 16*512*256 read_query (fp32)

  u16* wt = (u16*)d_ws;       // [128][2048] bf16, 512 KiB
  u16* wb = wt + NUMS * DIM;  // [2048][128] bf16, 512 KiB

  cvt_w_k<<<dim3(DIM / 32, NUMS / 32), dim3(32, 8), 0, stream>>>(weight, wb, wt);
  fused_k<<<dim3(ROWS_TOT / MTILE), dim3(512), 0, stream>>>(data, wb, wt, out);
}